// Round 1
// baseline (3517.853 us; speedup 1.0000x reference)
//
#include <hip/hip_runtime.h>
#include <hip/hip_bf16.h>

#define N_NODES 50000
#define N_EDGES 1600000
#define E_TOT   1650000   // N_EDGES + N_NODES self loops
#define N_PAIRS 2000000
#define N_GRAPHS 50
#define SCAN_NB 196       // ceil(N_NODES/256)

// ---------------- time embedding: h0[:, :128]=x, h0[:,128:384]=swish(feats@tW+tb)
__global__ void k_time_embed(const float* __restrict__ x, const float* __restrict__ t,
                             const float* __restrict__ tW, const float* __restrict__ tb,
                             float* __restrict__ h0) {
    int i = blockIdx.x;
    int tid = threadIdx.x;
    float ta = t[i];                       // T_LIMIT = 1.0
    float s = sinf(ta * 1.5707963267948966f);
    float c = cosf(ta * 1.5707963267948966f);
    if (tid < 128) h0[(size_t)i*384 + tid] = x[(size_t)i*128 + tid];
    float v = s*tW[tid] + c*tW[256+tid] + ta*tW[512+tid] + tb[tid];
    float sw = v / (1.f + __expf(-v));
    h0[(size_t)i*384 + 128 + tid] = sw;
}

// ---------------- CSR build ----------------
__global__ void k_edge_hist(const int* __restrict__ ei, int* __restrict__ deg) {
    int e = blockIdx.x*256 + threadIdx.x;
    if (e >= E_TOT) return;
    int dst = (e < N_EDGES) ? ei[N_EDGES + e] : (e - N_EDGES);
    atomicAdd(&deg[dst], 1);
}

__global__ void k_node_hist(const int* __restrict__ batch, int* __restrict__ gcnt) {
    int i = blockIdx.x*256 + threadIdx.x;
    if (i >= N_NODES) return;
    atomicAdd(&gcnt[batch[i]], 1);
}

__global__ void k_scan1(const int* __restrict__ deg, int* __restrict__ row_ptr,
                        int* __restrict__ bsums) {
    __shared__ int tmp[256];
    int tid = threadIdx.x;
    int i = blockIdx.x*256 + tid;
    int v = (i < N_NODES) ? deg[i] : 0;
    tmp[tid] = v; __syncthreads();
    for (int off = 1; off < 256; off <<= 1) {
        int tv = (tid >= off) ? tmp[tid-off] : 0;
        __syncthreads();
        tmp[tid] += tv;
        __syncthreads();
    }
    int inc = tmp[tid];
    if (i < N_NODES) row_ptr[i] = inc - v;     // block-local exclusive
    if (tid == 255) bsums[blockIdx.x] = inc;
}

__global__ void k_scan2(int* __restrict__ bsums, int nb) {
    __shared__ int tmp[256];
    int tid = threadIdx.x;
    int v = (tid < nb) ? bsums[tid] : 0;
    tmp[tid] = v; __syncthreads();
    for (int off = 1; off < 256; off <<= 1) {
        int tv = (tid >= off) ? tmp[tid-off] : 0;
        __syncthreads();
        tmp[tid] += tv;
        __syncthreads();
    }
    bsums[tid] = tmp[tid] - v;                 // exclusive over block sums
}

__global__ void k_scan3(int* __restrict__ row_ptr, const int* __restrict__ bsums,
                        int* __restrict__ cursor) {
    int i = blockIdx.x*256 + threadIdx.x;
    if (i < N_NODES) {
        int v = row_ptr[i] + bsums[blockIdx.x];
        row_ptr[i] = v;
        cursor[i] = v;
    }
    if (i == 0) row_ptr[N_NODES] = E_TOT;
}

__global__ void k_scatter(const int* __restrict__ ei, int* __restrict__ cursor,
                          int* __restrict__ csr_src) {
    int e = blockIdx.x*256 + threadIdx.x;
    if (e >= E_TOT) return;
    int src, dst;
    if (e < N_EDGES) { src = ei[e]; dst = ei[N_EDGES + e]; }
    else             { src = e - N_EDGES; dst = src; }
    int pos = atomicAdd(&cursor[dst], 1);
    csr_src[pos] = src;
}

// ---------------- dual GEMM: xl = A@Wl + bl, xr = A@Wr + br, A is [N,K], W [K,128]
template<int K>
__global__ __launch_bounds__(128) void k_gemm_dual(
    const float* __restrict__ A, const float* __restrict__ Wl, const float* __restrict__ Wr,
    const float* __restrict__ bl, const float* __restrict__ br,
    float* __restrict__ xl, float* __restrict__ xr) {
    __shared__ float Alds[8*K];
    int tid = threadIdx.x;
    size_t row0 = (size_t)blockIdx.x * 8;
    #pragma unroll
    for (int r = 0; r < 8; ++r)
        for (int kk = tid; kk < K; kk += 128)
            Alds[r*K + kk] = A[(row0 + r)*K + kk];
    __syncthreads();
    float accl[8], accr[8];
    #pragma unroll
    for (int r = 0; r < 8; ++r) { accl[r] = 0.f; accr[r] = 0.f; }
    for (int k = 0; k < K; ++k) {
        float wl = Wl[k*128 + tid];
        float wr = Wr[k*128 + tid];
        #pragma unroll
        for (int r = 0; r < 8; ++r) {
            float a = Alds[r*K + k];
            accl[r] += a * wl;
            accr[r] += a * wr;
        }
    }
    float bll = bl[tid], brr = br[tid];
    #pragma unroll
    for (int r = 0; r < 8; ++r) {
        xl[(row0+r)*128 + tid] = accl[r] + bll;
        xr[(row0+r)*128 + tid] = accr[r] + brr;
    }
}

// ---------------- GATv2 aggregation: one wave per node, online softmax.
// lane l holds channels 2l, 2l+1 (both in head l>>4). Fused graph-LN stats.
__global__ __launch_bounds__(256) void k_gat(
    const float* __restrict__ xl, const float* __restrict__ xr,
    const int* __restrict__ row_ptr, const int* __restrict__ csr_src,
    const float* __restrict__ att, const float* __restrict__ bias,
    const int* __restrict__ batch, float* __restrict__ hout,
    float* __restrict__ gsum, float* __restrict__ gsumsq) {
    int wave = (blockIdx.x * 256 + threadIdx.x) >> 6;
    int lane = threadIdx.x & 63;
    if (wave >= N_NODES) return;
    int i = wave;
    int c0 = lane * 2;
    int head = lane >> 4;
    float attv0 = att[head*32 + (c0 & 31)];
    float attv1 = att[head*32 + ((c0+1) & 31)];
    const float2* xl2 = (const float2*)xl;
    const float2* xr2 = (const float2*)xr;
    float2 xrv = xr2[(size_t)i*64 + lane];
    int p0 = row_ptr[i], p1 = row_ptr[i+1];
    float mrun = -1e30f, denom = 0.f, acc0 = 0.f, acc1 = 0.f;
    for (int p = p0; p < p1; ++p) {
        int s = csr_src[p];
        float2 xsv = xl2[(size_t)s*64 + lane];
        float m0 = xsv.x + xrv.x; m0 = (m0 >= 0.f) ? m0 : 0.2f*m0;
        float m1 = xsv.y + xrv.y; m1 = (m1 >= 0.f) ? m1 : 0.2f*m1;
        float part = m0*attv0 + m1*attv1;
        part += __shfl_xor(part, 1);
        part += __shfl_xor(part, 2);
        part += __shfl_xor(part, 4);
        part += __shfl_xor(part, 8);
        // part = logit for this lane's head
        float mnew = fmaxf(mrun, part);
        float scale = __expf(mrun - mnew);
        float w = __expf(part - mnew);
        denom = denom * scale + w;
        acc0  = acc0  * scale + w * xsv.x;
        acc1  = acc1  * scale + w * xsv.y;
        mrun = mnew;
    }
    float inv = 1.f / (denom + 1e-16f);
    float v0 = acc0 * inv + bias[c0];
    float v1 = acc1 * inv + bias[c0+1];
    hout[(size_t)i*128 + c0]     = v0;
    hout[(size_t)i*128 + c0 + 1] = v1;
    // fused graph-LN statistics
    float s1 = v0 + v1;
    float s2 = v0*v0 + v1*v1;
    #pragma unroll
    for (int off = 1; off < 64; off <<= 1) {
        s1 += __shfl_xor(s1, off);
        s2 += __shfl_xor(s2, off);
    }
    if (lane == 0) {
        int g = batch[i];
        atomicAdd(&gsum[g], s1);
        atomicAdd(&gsumsq[g], s2);
    }
}

// ---------------- graph layernorm apply ----------------
__global__ void k_ln(const float* __restrict__ hout, const int* __restrict__ batch,
                     const int* __restrict__ gcnt, const float* __restrict__ gsum,
                     const float* __restrict__ gsumsq, const float* __restrict__ w,
                     const float* __restrict__ b, float* __restrict__ hcur) {
    int idx = blockIdx.x*256 + threadIdx.x;
    if (idx >= N_NODES*128) return;
    int i = idx >> 7, c = idx & 127;
    int g = batch[i];
    float cnt = (float)gcnt[g] * 128.f;
    float mean = gsum[g] / cnt;
    float var = gsumsq[g] / cnt - mean*mean;
    var = fmaxf(var, 0.f);
    float rstd = rsqrtf(var + 1e-5f);
    hcur[idx] = (hout[idx] - mean) * rstd * w[c] + b[c];
}

// ---------------- pair scoring: 32 lanes per pair ----------------
__global__ __launch_bounds__(256) void k_pairs(
    const float* __restrict__ h, const int* __restrict__ pi,
    const float* __restrict__ lW, const float* __restrict__ lb,
    float* __restrict__ out) {
    int grp = (blockIdx.x*256 + threadIdx.x) >> 5;
    int q = threadIdx.x & 31;
    if (grp >= N_PAIRS) return;
    int p0 = pi[grp], p1 = pi[N_PAIRS + grp];
    const float4* h4 = (const float4*)h;
    const float4* w4 = (const float4*)lW;
    float4 a = h4[(size_t)p0*32 + q];
    float4 b = h4[(size_t)p1*32 + q];
    float4 w = w4[q];
    float part = a.x*b.x*w.x + a.y*b.y*w.y + a.z*b.z*w.z + a.w*b.w*w.w;
    part += __shfl_xor(part, 1);
    part += __shfl_xor(part, 2);
    part += __shfl_xor(part, 4);
    part += __shfl_xor(part, 8);
    part += __shfl_xor(part, 16);
    if (q == 0) out[grp] = 1.f / (1.f + __expf(-(part + lb[0])));
}

extern "C" void kernel_launch(void* const* d_in, const int* in_sizes, int n_in,
                              void* d_out, int out_size, void* d_ws, size_t ws_size,
                              hipStream_t stream) {
    const float* x     = (const float*)d_in[0];
    const float* t     = (const float*)d_in[1];
    const int*   ei    = (const int*)  d_in[2];
    const int*   pi    = (const int*)  d_in[3];
    const int*   batch = (const int*)  d_in[4];
    const float* tW    = (const float*)d_in[5];
    const float* tb    = (const float*)d_in[6];
    const float* W0l   = (const float*)d_in[7];
    const float* b0l   = (const float*)d_in[8];
    const float* W0r   = (const float*)d_in[9];
    const float* b0r   = (const float*)d_in[10];
    const float* att0  = (const float*)d_in[11];
    const float* bias0 = (const float*)d_in[12];
    const float* Wl    = (const float*)d_in[13];
    const float* bl    = (const float*)d_in[14];
    const float* Wr    = (const float*)d_in[15];
    const float* br    = (const float*)d_in[16];
    const float* att   = (const float*)d_in[17];
    const float* bias  = (const float*)d_in[18];
    const float* lnw   = (const float*)d_in[19];
    const float* lnb   = (const float*)d_in[20];
    const float* lW    = (const float*)d_in[21];
    const float* lb    = (const float*)d_in[22];
    float* out = (float*)d_out;

    char* ws = (char*)d_ws;
    size_t off = 0;
    auto walloc = [&](size_t bytes) -> void* {
        void* p = ws + off;
        off += (bytes + 255) & ~(size_t)255;
        return p;
    };
    float* h0      = (float*)walloc((size_t)N_NODES*384*4);
    float* hcur    = (float*)walloc((size_t)N_NODES*128*4);
    float* hout    = (float*)walloc((size_t)N_NODES*128*4);
    float* xl      = (float*)walloc((size_t)N_NODES*128*4);
    float* xr      = (float*)walloc((size_t)N_NODES*128*4);
    int*   deg     = (int*)  walloc((size_t)N_NODES*4);        // reused as cursor
    int*   row_ptr = (int*)  walloc((size_t)(N_NODES+1)*4);
    int*   csr_src = (int*)  walloc((size_t)E_TOT*4);
    int*   bsums   = (int*)  walloc(256*4);
    int*   gcnt    = (int*)  walloc(64*4);
    float* stats   = (float*)walloc(4*2*64*4);                 // [layer][sum|sumsq][64]

    hipMemsetAsync(deg, 0, (size_t)N_NODES*4, stream);
    hipMemsetAsync(gcnt, 0, 64*4, stream);
    hipMemsetAsync(stats, 0, 4*2*64*4, stream);

    k_time_embed<<<N_NODES, 256, 0, stream>>>(x, t, tW, tb, h0);
    k_edge_hist<<<(E_TOT+255)/256, 256, 0, stream>>>(ei, deg);
    k_node_hist<<<(N_NODES+255)/256, 256, 0, stream>>>(batch, gcnt);
    k_scan1<<<SCAN_NB, 256, 0, stream>>>(deg, row_ptr, bsums);
    k_scan2<<<1, 256, 0, stream>>>(bsums, SCAN_NB);
    k_scan3<<<SCAN_NB, 256, 0, stream>>>(row_ptr, bsums, deg);   // deg becomes cursor
    k_scatter<<<(E_TOT+255)/256, 256, 0, stream>>>(ei, deg, csr_src);

    for (int L = 0; L < 4; ++L) {
        if (L == 0)
            k_gemm_dual<384><<<N_NODES/8, 128, 0, stream>>>(h0, W0l, W0r, b0l, b0r, xl, xr);
        else
            k_gemm_dual<128><<<N_NODES/8, 128, 0, stream>>>(hcur, Wl + (size_t)(L-1)*128*128,
                                                            Wr + (size_t)(L-1)*128*128,
                                                            bl + (L-1)*128, br + (L-1)*128, xl, xr);
        const float* attL  = (L == 0) ? att0  : att  + (size_t)(L-1)*128;
        const float* biasL = (L == 0) ? bias0 : bias + (size_t)(L-1)*128;
        float* gsum   = stats + L*128;
        float* gsumsq = stats + L*128 + 64;
        k_gat<<<N_NODES/4, 256, 0, stream>>>(xl, xr, row_ptr, csr_src, attL, biasL,
                                             batch, hout, gsum, gsumsq);
        k_ln<<<(N_NODES*128+255)/256, 256, 0, stream>>>(hout, batch, gcnt, gsum, gsumsq,
                                                        lnw + L*128, lnb + L*128, hcur);
    }

    k_pairs<<<((size_t)N_PAIRS*32 + 255)/256, 256, 0, stream>>>(hcur, pi, lW, lb, out);
}